// Round 8
// baseline (4422.539 us; speedup 1.0000x reference)
//
#include <hip/hip_runtime.h>
#include <hip/hip_bf16.h>
#include <hip/hip_cooperative_groups.h>

namespace cg = cooperative_groups;

#define BATCH 8192
#define INPUT 64
#define HIDDEN 512
#define OUTPUT 64
#define STEPS 100

typedef __bf16 bf16x8 __attribute__((ext_vector_type(8)));
typedef float f32x16 __attribute__((ext_vector_type(16)));

__device__ __forceinline__ float sigf(float x) { return 1.0f / (1.0f + __expf(-x)); }
__device__ __forceinline__ float tanh_fast(float x) { return 1.0f - 2.0f / (1.0f + __expf(2.0f * x)); }

__device__ __forceinline__ void load_lds16(const void* g, void* l) {
    __builtin_amdgcn_global_load_lds((const __attribute__((address_space(1))) void*)g,
                                     (__attribute__((address_space(3))) void*)l, 16, 0, 0);
}

// ---------------- fold: wcomb = Whh + Wih@Wout (fp32), bias1 = b_lstm + Wih@b_out ----------------
// inp_t = out_{t-1} = h_t@Wout^T + b_out  =>  for t>=1:
//   gates_t = h_t @ (Whh + Wih@Wout)^T + (b_lstm + Wih@b_out).   t=0: plain Whh/b_lstm (inp_0=0).
__global__ __launch_bounds__(64) void fold_weights(
    const float* __restrict__ Wih, const float* __restrict__ Whh,
    const float* __restrict__ Wout, const float* __restrict__ b_lstm,
    const float* __restrict__ b_out, float* __restrict__ wcomb, float* __restrict__ bias1) {
    __shared__ float wrow[64];
    const int n = blockIdx.x;
    const int tid = threadIdx.x;
    wrow[tid] = Wih[n * 64 + tid];
    __syncthreads();
    for (int k = tid; k < HIDDEN; k += 64) {
        float s = Whh[n * HIDDEN + k];
#pragma unroll 16
        for (int o = 0; o < 64; ++o) s += wrow[o] * Wout[o * HIDDEN + k];
        wcomb[n * HIDDEN + k] = s;
    }
    if (tid == 0) {
        float s = b_lstm[n];
        for (int o = 0; o < 64; ++o) s += wrow[o] * b_out[o];
        bias1[n] = s;
    }
}

// ---------------- pack (fp32 -> bf16), swizzled fragment-ordered ----------------
// P layout: [16 cb][8 ck][128 row][64 e'];  row=g*32+cc -> n=g*512+cb*32+cc;
// content at e' is k = ck*64 + (e' ^ ((row&7)<<3)).
__global__ void pack_weights(const float* __restrict__ Whh, const float* __restrict__ wcomb,
                             const float* __restrict__ Wout,
                             __bf16* __restrict__ P0, __bf16* __restrict__ P1,
                             __bf16* __restrict__ wout) {
    const int NP = 16 * 8 * 128 * 64;
    for (int idx = blockIdx.x * 256 + threadIdx.x; idx < NP; idx += gridDim.x * 256) {
        int e_p = idx & 63;
        int row = (idx >> 6) & 127;
        int ck  = (idx >> 13) & 7;
        int cb  = idx >> 16;
        int k = ck * 64 + (e_p ^ ((row & 7) << 3));
        int n = ((row >> 5) << 9) + (cb << 5) + (row & 31);
        P0[idx] = (__bf16)Whh[n * HIDDEN + k];
        P1[idx] = (__bf16)wcomb[n * HIDDEN + k];
    }
    for (int idx = blockIdx.x * 256 + threadIdx.x; idx < OUTPUT * HIDDEN; idx += gridDim.x * 256)
        wout[idx] = (__bf16)Wout[idx];
}

__global__ void init_state(const float* __restrict__ h0, const float* __restrict__ c0,
                           __bf16* __restrict__ h, float* __restrict__ c) {
    int idx = blockIdx.x * 256 + threadIdx.x;
    if (idx < BATCH * HIDDEN) {
        int j = idx & (HIDDEN - 1);
        h[idx] = (__bf16)h0[j];
        c[idx] = c0[j];
    }
}

// ================= persistent cooperative kernel: all 100 steps in one dispatch =================
// 256 blocks x 512 thr (8 waves = 2/SIMD; 1 block/CU -> co-residency trivially satisfiable).
// Block (rb2,cb): rows [rb2*512,+512) x cols [cb*32,+32) per gate; wave w owns 64 rows.
// Per step: gates GEMM (8 LDS-dbuf chunks, math identical to split lstm_step) -> cell ->
// grid.sync -> waves 0,1 compute out_t (math identical to split out_step).
// One sync/step ordering (verified): hn-writes(t) [pre-sync t] happen-before out(t)-reads and
// gates(t+1)-reads [post-sync t]; gates(t+1) writes buffer last READ at out(t-1)/gates(t),
// both pre-sync(t) -> safe.
__global__ __launch_bounds__(512, 2) void lstm_persistent(
    const __bf16* __restrict__ P0, const __bf16* __restrict__ P1,
    const float* __restrict__ bias0, const float* __restrict__ bias1,
    const __bf16* __restrict__ wout, const float* __restrict__ b_out,
    float* __restrict__ c, __bf16* __restrict__ hA, __bf16* __restrict__ hB,
    float* __restrict__ out) {

    cg::grid_group grid = cg::this_grid();
    __shared__ __bf16 bsm[2][128][64];  // 32 KB

    const int lane = threadIdx.x & 63;
    const int wave = threadIdx.x >> 6;          // 0..7
    const int r = lane & 31;
    const int koff = (lane >> 5) * 8;

    const int bid = blockIdx.x;                 // 256 blocks, 8 | 256
    const int j = bid >> 3;
    const int rb2 = ((bid & 7) << 1) | (j & 1); // 0..15: XCD x owns rows [1024x, 1024x+1024)
    const int cb = j >> 1;                      // 0..15

    const int mBase = rb2 * 512 + wave * 64;
    const int ncol = cb * 32 + r;
    const int arow = mBase + r;
    const int rbase = 4 * (lane >> 5);

    // stage 16KB chunk: 8 waves x 2 instr x 1KB, coalesced, linear LDS dest
    auto stage = [&](const __bf16* P, int ck, int buf) {
        const char* src = (const char*)P + (((size_t)(cb * 8 + ck)) << 14)
                          + ((size_t)(wave * 2) << 10) + lane * 16;
        char* dst = (char*)&bsm[buf][0][0] + ((size_t)(wave * 2) << 10);
        load_lds16(src, dst);
        load_lds16(src + 1024, dst + 1024);
    };

    stage(P0, 0, 0);
    __syncthreads();

    for (int t = 0; t < STEPS; ++t) {
        const __bf16* hc = (t & 1) ? hB : hA;
        __bf16*       hn = (t & 1) ? hA : hB;
        const __bf16* P    = (t == 0) ? P0 : P1;
        const float*  bias = (t == 0) ? bias0 : bias1;

        f32x16 acc[4][2];
#pragma unroll
        for (int g = 0; g < 4; ++g)
#pragma unroll
            for (int m = 0; m < 2; ++m)
#pragma unroll
                for (int v = 0; v < 16; ++v) acc[g][m][v] = 0.0f;

        int buf = 0;
        for (int ck = 0; ck < 8; ++ck) {
            if (ck < 7) stage(P, ck + 1, buf ^ 1);
            else        stage(P1, 0, buf ^ 1);   // next step's chunk 0 (always P1)

            const __bf16* ap = hc + arow * HIDDEN + ck * 64;
            const __bf16* bb = &bsm[buf][0][0];
#pragma unroll
            for (int kk = 0; kk < 4; ++kk) {
                bf16x8 a0 = *reinterpret_cast<const bf16x8*>(ap + kk * 16 + koff);
                bf16x8 a1 = *reinterpret_cast<const bf16x8*>(ap + 32 * HIDDEN + kk * 16 + koff);
                const int eo = (kk * 16 + koff) ^ ((r & 7) << 3);
#pragma unroll
                for (int g = 0; g < 4; ++g) {
                    bf16x8 b = *reinterpret_cast<const bf16x8*>(bb + (g * 32 + r) * 64 + eo);
                    acc[g][0] = __builtin_amdgcn_mfma_f32_32x32x16_bf16(a0, b, acc[g][0], 0, 0, 0);
                    acc[g][1] = __builtin_amdgcn_mfma_f32_32x32x16_bf16(a1, b, acc[g][1], 0, 0, 0);
                }
            }
            __syncthreads();
            buf ^= 1;
        }

        const float bi = bias[0 * HIDDEN + ncol];
        const float bf = bias[1 * HIDDEN + ncol];
        const float bg = bias[2 * HIDDEN + ncol];
        const float bo = bias[3 * HIDDEN + ncol];
#pragma unroll
        for (int m = 0; m < 2; ++m) {
#pragma unroll
            for (int v = 0; v < 16; ++v) {
                int row = mBase + m * 32 + (v & 3) + 8 * (v >> 2) + rbase;
                float iv = sigf(acc[0][m][v] + bi);
                float fv = sigf(acc[1][m][v] + bf);
                float gv = tanh_fast(acc[2][m][v] + bg);
                float ov = sigf(acc[3][m][v] + bo);
                float cold = c[row * HIDDEN + ncol];
                float cnew = fv * cold + iv * gv;
                c[row * HIDDEN + ncol] = cnew;
                hn[row * HIDDEN + ncol] = (__bf16)(ov * tanh_fast(cnew));
            }
        }

        grid.sync();   // h_next globally visible

        if (wave < 2) {  // out_t = h_next @ Wout^T + b_out : 256 blocks x 2 waves
            const int mB = ((bid & 7) << 10) + ((bid >> 3) << 5);  // same XCD slab
            const int nB = wave * 32;
            f32x16 oacc;
#pragma unroll
            for (int v = 0; v < 16; ++v) oacc[v] = 0.0f;
            const __bf16* ap = hn + (mB + r) * HIDDEN + koff;
            const __bf16* bp = wout + (nB + r) * HIDDEN + koff;
#pragma unroll 8
            for (int kk = 0; kk < HIDDEN / 16; ++kk) {
                bf16x8 a = *reinterpret_cast<const bf16x8*>(ap + kk * 16);
                bf16x8 b = *reinterpret_cast<const bf16x8*>(bp + kk * 16);
                oacc = __builtin_amdgcn_mfma_f32_32x32x16_bf16(a, b, oacc, 0, 0, 0);
            }
            const int col = nB + r;
            const float bv = b_out[col];
#pragma unroll
            for (int v = 0; v < 16; ++v) {
                int row = mB + (v & 3) + 8 * (v >> 2) + rbase;
                out[row * (STEPS * OUTPUT) + t * OUTPUT + col] = oacc[v] + bv;
            }
        }
        // no second sync needed: next gates only READ hn; that buffer is next WRITTEN at t+2
    }
}

// ================= fallback split kernels (R7-proven, byte-identical math) =================
__global__ __launch_bounds__(256, 2) void lstm_step(
    const __bf16* __restrict__ h_in, const __bf16* __restrict__ P,
    const float* __restrict__ bias,
    float* __restrict__ c, __bf16* __restrict__ h_out) {

    __shared__ __bf16 bsm[2][128][64];

    const int lane = threadIdx.x & 63;
    const int wave = threadIdx.x >> 6;
    const int r = lane & 31;
    const int koff = (lane >> 5) * 8;

    const int bid = blockIdx.x;
    const int j = bid >> 3;
    const int rb = ((bid & 7) << 2) | (j & 3);
    const int cb = j >> 2;

    const int mBase = rb * 256 + wave * 64;
    const int ncol = cb * 32 + r;
    const int arow = mBase + r;

    f32x16 acc[4][2];
#pragma unroll
    for (int g = 0; g < 4; ++g)
#pragma unroll
        for (int m = 0; m < 2; ++m)
#pragma unroll
            for (int v = 0; v < 16; ++v) acc[g][m][v] = 0.0f;

    auto stage = [&](int ck, int buf) {
        const char* src = (const char*)P + (((size_t)(cb * 8 + ck)) << 14)
                          + ((size_t)(wave * 4) << 10) + lane * 16;
        char* dst = (char*)&bsm[buf][0][0] + ((size_t)(wave * 4) << 10);
#pragma unroll
        for (int i = 0; i < 4; ++i)
            load_lds16(src + i * 1024, dst + i * 1024);
    };

    stage(0, 0);
    __syncthreads();

    int buf = 0;
    for (int ck = 0; ck < 8; ++ck) {
        if (ck < 7) stage(ck + 1, buf ^ 1);

        const __bf16* ap = h_in + arow * HIDDEN + ck * 64;
        const __bf16* bb = &bsm[buf][0][0];
#pragma unroll
        for (int kk = 0; kk < 4; ++kk) {
            bf16x8 a0 = *reinterpret_cast<const bf16x8*>(ap + kk * 16 + koff);
            bf16x8 a1 = *reinterpret_cast<const bf16x8*>(ap + 32 * HIDDEN + kk * 16 + koff);
            const int eo = (kk * 16 + koff) ^ ((r & 7) << 3);
#pragma unroll
            for (int g = 0; g < 4; ++g) {
                bf16x8 b = *reinterpret_cast<const bf16x8*>(bb + (g * 32 + r) * 64 + eo);
                acc[g][0] = __builtin_amdgcn_mfma_f32_32x32x16_bf16(a0, b, acc[g][0], 0, 0, 0);
                acc[g][1] = __builtin_amdgcn_mfma_f32_32x32x16_bf16(a1, b, acc[g][1], 0, 0, 0);
            }
        }
        __syncthreads();
        buf ^= 1;
    }

    const float bi = bias[0 * HIDDEN + ncol];
    const float bf = bias[1 * HIDDEN + ncol];
    const float bg = bias[2 * HIDDEN + ncol];
    const float bo = bias[3 * HIDDEN + ncol];
    const int rbase = 4 * (lane >> 5);
#pragma unroll
    for (int m = 0; m < 2; ++m) {
#pragma unroll
        for (int v = 0; v < 16; ++v) {
            int row = mBase + m * 32 + (v & 3) + 8 * (v >> 2) + rbase;
            float iv = sigf(acc[0][m][v] + bi);
            float fv = sigf(acc[1][m][v] + bf);
            float gv = tanh_fast(acc[2][m][v] + bg);
            float ov = sigf(acc[3][m][v] + bo);
            float cold = c[row * HIDDEN + ncol];
            float cnew = fv * cold + iv * gv;
            c[row * HIDDEN + ncol] = cnew;
            h_out[row * HIDDEN + ncol] = (__bf16)(ov * tanh_fast(cnew));
        }
    }
}

__global__ __launch_bounds__(128, 2) void out_step(
    const __bf16* __restrict__ h, const __bf16* __restrict__ wout,
    const float* __restrict__ b_out, float* __restrict__ out, int t) {

    const int lane = threadIdx.x & 63;
    const int wave = threadIdx.x >> 6;
    const int r = lane & 31;
    const int koff = (lane >> 5) * 8;

    const int bid = blockIdx.x;
    const int mBase = ((bid & 7) << 10) + ((bid >> 3) << 5);
    const int nBase = wave * 32;

    f32x16 acc;
#pragma unroll
    for (int v = 0; v < 16; ++v) acc[v] = 0.0f;

    const __bf16* ap = h + (mBase + r) * HIDDEN + koff;
    const __bf16* bp = wout + (nBase + r) * HIDDEN + koff;
#pragma unroll 8
    for (int kk = 0; kk < HIDDEN / 16; ++kk) {
        bf16x8 a = *reinterpret_cast<const bf16x8*>(ap + kk * 16);
        bf16x8 b = *reinterpret_cast<const bf16x8*>(bp + kk * 16);
        acc = __builtin_amdgcn_mfma_f32_32x32x16_bf16(a, b, acc, 0, 0, 0);
    }

    const int col = nBase + r;
    const float bv = b_out[col];
    const int rbase = 4 * (lane >> 5);
#pragma unroll
    for (int v = 0; v < 16; ++v) {
        int row = mBase + (v & 3) + 8 * (v >> 2) + rbase;
        out[row * (STEPS * OUTPUT) + t * OUTPUT + col] = acc[v] + bv;
    }
}

extern "C" void kernel_launch(void* const* d_in, const int* in_sizes, int n_in,
                              void* d_out, int out_size, void* d_ws, size_t ws_size,
                              hipStream_t stream) {
    const float* W_ih   = (const float*)d_in[1];
    const float* W_hh   = (const float*)d_in[2];
    const float* b_lstm = (const float*)d_in[3];
    const float* h0     = (const float*)d_in[4];
    const float* c0     = (const float*)d_in[5];
    const float* W_out  = (const float*)d_in[6];
    const float* b_out  = (const float*)d_in[7];
    float* out = (float*)d_out;

    char* ws = (char*)d_ws;
    size_t off = 0;
    auto alloc = [&](size_t bytes) -> void* {
        void* p = ws + off;
        off += (bytes + 255) & ~(size_t)255;
        return p;
    };
    float*  wcomb = (float*)alloc((size_t)4 * HIDDEN * HIDDEN * 4);
    float*  bias1 = (float*)alloc((size_t)4 * HIDDEN * 4);
    __bf16* P0    = (__bf16*)alloc((size_t)16 * 8 * 128 * 64 * 2);
    __bf16* P1    = (__bf16*)alloc((size_t)16 * 8 * 128 * 64 * 2);
    __bf16* wout  = (__bf16*)alloc((size_t)OUTPUT * HIDDEN * 2);
    __bf16* hA    = (__bf16*)alloc((size_t)BATCH * HIDDEN * 2);
    __bf16* hB    = (__bf16*)alloc((size_t)BATCH * HIDDEN * 2);
    float*  c     = (float*)alloc((size_t)BATCH * HIDDEN * 4);

    fold_weights<<<4 * HIDDEN, 64, 0, stream>>>(W_ih, W_hh, W_out, b_lstm, b_out, wcomb, bias1);
    pack_weights<<<2048, 256, 0, stream>>>(W_hh, wcomb, W_out, P0, P1, wout);
    init_state<<<(BATCH * HIDDEN + 255) / 256, 256, 0, stream>>>(h0, c0, hA, c);

    // --- cooperative persistent path with deterministic fallback ---
    bool coop = false;
    int maxAct = 0;
    if (hipOccupancyMaxActiveBlocksPerMultiprocessor(&maxAct, lstm_persistent, 512, 0)
            == hipSuccess && maxAct >= 1) {
        const __bf16* cP0 = P0; const __bf16* cP1 = P1;
        const float* cb0 = b_lstm; const float* cb1 = bias1;
        const __bf16* cwo = wout; const float* cbo = b_out;
        float* cc = c; __bf16* chA = hA; __bf16* chB = hB; float* cout = out;
        void* args[] = { (void*)&cP0, (void*)&cP1, (void*)&cb0, (void*)&cb1,
                         (void*)&cwo, (void*)&cbo, (void*)&cc, (void*)&chA, (void*)&chB,
                         (void*)&cout };
        coop = (hipLaunchCooperativeKernel((void*)lstm_persistent, dim3(256), dim3(512),
                                           args, 0, stream) == hipSuccess);
    }
    if (!coop) {
        __bf16* hc = hA;
        __bf16* hn = hB;
        for (int t = 0; t < STEPS; ++t) {
            const __bf16* P    = (t == 0) ? P0 : P1;
            const float*  bias = (t == 0) ? b_lstm : bias1;
            lstm_step<<<512, 256, 0, stream>>>(hc, P, bias, c, hn);
            out_step<<<BATCH / 32, 128, 0, stream>>>(hn, wout, b_out, out, t);
            __bf16* tmp = hc; hc = hn; hn = tmp;
        }
    }
}

// Round 9
// 4395.808 us; speedup vs baseline: 1.0061x; 1.0061x over previous
//
#include <hip/hip_runtime.h>
#include <hip/hip_bf16.h>
#include <hip/hip_cooperative_groups.h>

namespace cg = cooperative_groups;

#define BATCH 8192
#define INPUT 64
#define HIDDEN 512
#define OUTPUT 64
#define STEPS 100

typedef __bf16 bf16x8 __attribute__((ext_vector_type(8)));
typedef float f32x16 __attribute__((ext_vector_type(16)));

__device__ __forceinline__ float sigf(float x) { return 1.0f / (1.0f + __expf(-x)); }
__device__ __forceinline__ float tanh_fast(float x) { return 1.0f - 2.0f / (1.0f + __expf(2.0f * x)); }

__device__ __forceinline__ void load_lds16(const void* g, void* l) {
    __builtin_amdgcn_global_load_lds((const __attribute__((address_space(1))) void*)g,
                                     (__attribute__((address_space(3))) void*)l, 16, 0, 0);
}

// ---------------- fold: wcomb = Whh + Wih@Wout (fp32), bias1 = b_lstm + Wih@b_out ----------------
// inp_t = out_{t-1} = h_t@Wout^T + b_out  =>  for t>=1:
//   gates_t = h_t @ (Whh + Wih@Wout)^T + (b_lstm + Wih@b_out).   t=0: plain Whh/b_lstm (inp_0=0).
__global__ __launch_bounds__(64) void fold_weights(
    const float* __restrict__ Wih, const float* __restrict__ Whh,
    const float* __restrict__ Wout, const float* __restrict__ b_lstm,
    const float* __restrict__ b_out, float* __restrict__ wcomb, float* __restrict__ bias1) {
    __shared__ float wrow[64];
    const int n = blockIdx.x;
    const int tid = threadIdx.x;
    wrow[tid] = Wih[n * 64 + tid];
    __syncthreads();
    for (int k = tid; k < HIDDEN; k += 64) {
        float s = Whh[n * HIDDEN + k];
#pragma unroll 16
        for (int o = 0; o < 64; ++o) s += wrow[o] * Wout[o * HIDDEN + k];
        wcomb[n * HIDDEN + k] = s;
    }
    if (tid == 0) {
        float s = b_lstm[n];
        for (int o = 0; o < 64; ++o) s += wrow[o] * b_out[o];
        bias1[n] = s;
    }
}

// ---------------- pack (fp32 -> bf16), swizzled fragment-ordered ----------------
// P layout: [16 cb][8 ck][128 row][64 e'];  row=g*32+cc -> n=g*512+cb*32+cc;
// content at e' is k = ck*64 + (e' ^ ((row&7)<<3)).
__global__ void pack_weights(const float* __restrict__ Whh, const float* __restrict__ wcomb,
                             const float* __restrict__ Wout,
                             __bf16* __restrict__ P0, __bf16* __restrict__ P1,
                             __bf16* __restrict__ wout) {
    const int NP = 16 * 8 * 128 * 64;
    for (int idx = blockIdx.x * 256 + threadIdx.x; idx < NP; idx += gridDim.x * 256) {
        int e_p = idx & 63;
        int row = (idx >> 6) & 127;
        int ck  = (idx >> 13) & 7;
        int cb  = idx >> 16;
        int k = ck * 64 + (e_p ^ ((row & 7) << 3));
        int n = ((row >> 5) << 9) + (cb << 5) + (row & 31);
        P0[idx] = (__bf16)Whh[n * HIDDEN + k];
        P1[idx] = (__bf16)wcomb[n * HIDDEN + k];
    }
    for (int idx = blockIdx.x * 256 + threadIdx.x; idx < OUTPUT * HIDDEN; idx += gridDim.x * 256)
        wout[idx] = (__bf16)Wout[idx];
}

__global__ void init_state(const float* __restrict__ h0, const float* __restrict__ c0,
                           __bf16* __restrict__ h, float* __restrict__ c) {
    int idx = blockIdx.x * 256 + threadIdx.x;
    if (idx < BATCH * HIDDEN) {
        int j = idx & (HIDDEN - 1);
        h[idx] = (__bf16)h0[j];
        c[idx] = c0[j];   // used by fallback path only; coop keeps c in registers
    }
}

// ================= persistent cooperative kernel: all 100 steps, c in REGISTERS =================
// 256 blocks x 512 thr (8 waves, 1 block/CU). Block (rb2,cb): rows [rb2*512,+512) x cols
// [cb*32,+32) per gate; thread owns the SAME 32 (row,col) cells for all steps -> c lives in
// 32 VGPRs (kills the 32 MB/step global RMW that R8's counters showed thrashing L2->L3).
// Per-XCD L2 resident set is now hA 1MB + hB 1MB + P 2MB = 4MB.
// One sync/step ordering (R8-proven): hn-writes(t) pre-sync -> out(t)/gates(t+1) reads post-sync;
// gates(t+1) writes the buffer last read pre-sync(t).
__global__ __launch_bounds__(512, 2) void lstm_persistent(
    const __bf16* __restrict__ P0, const __bf16* __restrict__ P1,
    const float* __restrict__ bias0, const float* __restrict__ bias1,
    const __bf16* __restrict__ wout, const float* __restrict__ b_out,
    const float* __restrict__ c0, __bf16* __restrict__ hA, __bf16* __restrict__ hB,
    float* __restrict__ out) {

    cg::grid_group grid = cg::this_grid();
    __shared__ __bf16 bsm[2][128][64];  // 32 KB

    const int lane = threadIdx.x & 63;
    const int wave = threadIdx.x >> 6;          // 0..7
    const int r = lane & 31;
    const int koff = (lane >> 5) * 8;

    const int bid = blockIdx.x;                 // 256 blocks, 8 | 256
    const int j = bid >> 3;
    const int rb2 = ((bid & 7) << 1) | (j & 1); // 0..15: XCD x owns rows [1024x, 1024x+1024)
    const int cb = j >> 1;                      // 0..15

    const int mBase = rb2 * 512 + wave * 64;
    const int ncol = cb * 32 + r;
    const int arow = mBase + r;
    const int rbase = 4 * (lane >> 5);

    // cell state in registers: c[row][ncol] = c0[ncol] initially (same for all 32 owned cells)
    float creg[2][16];
    {
        const float cinit = c0[ncol];
#pragma unroll
        for (int m = 0; m < 2; ++m)
#pragma unroll
            for (int v = 0; v < 16; ++v) creg[m][v] = cinit;
    }

    // stage 16KB chunk: 8 waves x 2 instr x 1KB, coalesced, linear LDS dest
    auto stage = [&](const __bf16* P, int ck, int buf) {
        const char* src = (const char*)P + (((size_t)(cb * 8 + ck)) << 14)
                          + ((size_t)(wave * 2) << 10) + lane * 16;
        char* dst = (char*)&bsm[buf][0][0] + ((size_t)(wave * 2) << 10);
        load_lds16(src, dst);
        load_lds16(src + 1024, dst + 1024);
    };

    stage(P0, 0, 0);
    __syncthreads();

    for (int t = 0; t < STEPS; ++t) {
        const __bf16* hc = (t & 1) ? hB : hA;
        __bf16*       hn = (t & 1) ? hA : hB;
        const __bf16* P    = (t == 0) ? P0 : P1;
        const float*  bias = (t == 0) ? bias0 : bias1;

        f32x16 acc[4][2];
#pragma unroll
        for (int g = 0; g < 4; ++g)
#pragma unroll
            for (int m = 0; m < 2; ++m)
#pragma unroll
                for (int v = 0; v < 16; ++v) acc[g][m][v] = 0.0f;

        int buf = 0;
        for (int ck = 0; ck < 8; ++ck) {
            if (ck < 7) stage(P, ck + 1, buf ^ 1);
            else        stage(P1, 0, buf ^ 1);   // next step's chunk 0 (always P1)

            const __bf16* ap = hc + arow * HIDDEN + ck * 64;
            const __bf16* bb = &bsm[buf][0][0];
#pragma unroll
            for (int kk = 0; kk < 4; ++kk) {
                bf16x8 a0 = *reinterpret_cast<const bf16x8*>(ap + kk * 16 + koff);
                bf16x8 a1 = *reinterpret_cast<const bf16x8*>(ap + 32 * HIDDEN + kk * 16 + koff);
                const int eo = (kk * 16 + koff) ^ ((r & 7) << 3);
#pragma unroll
                for (int g = 0; g < 4; ++g) {
                    bf16x8 b = *reinterpret_cast<const bf16x8*>(bb + (g * 32 + r) * 64 + eo);
                    acc[g][0] = __builtin_amdgcn_mfma_f32_32x32x16_bf16(a0, b, acc[g][0], 0, 0, 0);
                    acc[g][1] = __builtin_amdgcn_mfma_f32_32x32x16_bf16(a1, b, acc[g][1], 0, 0, 0);
                }
            }
            __syncthreads();
            buf ^= 1;
        }

        const float bi = bias[0 * HIDDEN + ncol];
        const float bf = bias[1 * HIDDEN + ncol];
        const float bg = bias[2 * HIDDEN + ncol];
        const float bo = bias[3 * HIDDEN + ncol];
#pragma unroll
        for (int m = 0; m < 2; ++m) {
#pragma unroll
            for (int v = 0; v < 16; ++v) {
                int row = mBase + m * 32 + (v & 3) + 8 * (v >> 2) + rbase;
                float iv = sigf(acc[0][m][v] + bi);
                float fv = sigf(acc[1][m][v] + bf);
                float gv = tanh_fast(acc[2][m][v] + bg);
                float ov = sigf(acc[3][m][v] + bo);
                float cnew = fv * creg[m][v] + iv * gv;
                creg[m][v] = cnew;               // register-resident cell state
                hn[row * HIDDEN + ncol] = (__bf16)(ov * tanh_fast(cnew));
            }
        }

        grid.sync();   // h_next globally visible

        if (wave < 2) {  // out_t = h_next @ Wout^T + b_out : 256 blocks x 2 waves
            const int mB = ((bid & 7) << 10) + ((bid >> 3) << 5);  // same XCD slab
            const int nB = wave * 32;
            f32x16 oacc;
#pragma unroll
            for (int v = 0; v < 16; ++v) oacc[v] = 0.0f;
            const __bf16* ap = hn + (mB + r) * HIDDEN + koff;
            const __bf16* bp = wout + (nB + r) * HIDDEN + koff;
#pragma unroll 8
            for (int kk = 0; kk < HIDDEN / 16; ++kk) {
                bf16x8 a = *reinterpret_cast<const bf16x8*>(ap + kk * 16);
                bf16x8 b = *reinterpret_cast<const bf16x8*>(bp + kk * 16);
                oacc = __builtin_amdgcn_mfma_f32_32x32x16_bf16(a, b, oacc, 0, 0, 0);
            }
            const int col = nB + r;
            const float bv = b_out[col];
#pragma unroll
            for (int v = 0; v < 16; ++v) {
                int row = mB + (v & 3) + 8 * (v >> 2) + rbase;
                out[row * (STEPS * OUTPUT) + t * OUTPUT + col] = oacc[v] + bv;
            }
        }
        // no second sync: next gates only READ hn; that buffer is next WRITTEN at t+2
    }
}

// ================= fallback split kernels (R7-proven, global c) =================
__global__ __launch_bounds__(256, 2) void lstm_step(
    const __bf16* __restrict__ h_in, const __bf16* __restrict__ P,
    const float* __restrict__ bias,
    float* __restrict__ c, __bf16* __restrict__ h_out) {

    __shared__ __bf16 bsm[2][128][64];

    const int lane = threadIdx.x & 63;
    const int wave = threadIdx.x >> 6;
    const int r = lane & 31;
    const int koff = (lane >> 5) * 8;

    const int bid = blockIdx.x;
    const int j = bid >> 3;
    const int rb = ((bid & 7) << 2) | (j & 3);
    const int cb = j >> 2;

    const int mBase = rb * 256 + wave * 64;
    const int ncol = cb * 32 + r;
    const int arow = mBase + r;

    f32x16 acc[4][2];
#pragma unroll
    for (int g = 0; g < 4; ++g)
#pragma unroll
        for (int m = 0; m < 2; ++m)
#pragma unroll
            for (int v = 0; v < 16; ++v) acc[g][m][v] = 0.0f;

    auto stage = [&](int ck, int buf) {
        const char* src = (const char*)P + (((size_t)(cb * 8 + ck)) << 14)
                          + ((size_t)(wave * 4) << 10) + lane * 16;
        char* dst = (char*)&bsm[buf][0][0] + ((size_t)(wave * 4) << 10);
#pragma unroll
        for (int i = 0; i < 4; ++i)
            load_lds16(src + i * 1024, dst + i * 1024);
    };

    stage(0, 0);
    __syncthreads();

    int buf = 0;
    for (int ck = 0; ck < 8; ++ck) {
        if (ck < 7) stage(ck + 1, buf ^ 1);

        const __bf16* ap = h_in + arow * HIDDEN + ck * 64;
        const __bf16* bb = &bsm[buf][0][0];
#pragma unroll
        for (int kk = 0; kk < 4; ++kk) {
            bf16x8 a0 = *reinterpret_cast<const bf16x8*>(ap + kk * 16 + koff);
            bf16x8 a1 = *reinterpret_cast<const bf16x8*>(ap + 32 * HIDDEN + kk * 16 + koff);
            const int eo = (kk * 16 + koff) ^ ((r & 7) << 3);
#pragma unroll
            for (int g = 0; g < 4; ++g) {
                bf16x8 b = *reinterpret_cast<const bf16x8*>(bb + (g * 32 + r) * 64 + eo);
                acc[g][0] = __builtin_amdgcn_mfma_f32_32x32x16_bf16(a0, b, acc[g][0], 0, 0, 0);
                acc[g][1] = __builtin_amdgcn_mfma_f32_32x32x16_bf16(a1, b, acc[g][1], 0, 0, 0);
            }
        }
        __syncthreads();
        buf ^= 1;
    }

    const float bi = bias[0 * HIDDEN + ncol];
    const float bf = bias[1 * HIDDEN + ncol];
    const float bg = bias[2 * HIDDEN + ncol];
    const float bo = bias[3 * HIDDEN + ncol];
    const int rbase = 4 * (lane >> 5);
#pragma unroll
    for (int m = 0; m < 2; ++m) {
#pragma unroll
        for (int v = 0; v < 16; ++v) {
            int row = mBase + m * 32 + (v & 3) + 8 * (v >> 2) + rbase;
            float iv = sigf(acc[0][m][v] + bi);
            float fv = sigf(acc[1][m][v] + bf);
            float gv = tanh_fast(acc[2][m][v] + bg);
            float ov = sigf(acc[3][m][v] + bo);
            float cold = c[row * HIDDEN + ncol];
            float cnew = fv * cold + iv * gv;
            c[row * HIDDEN + ncol] = cnew;
            h_out[row * HIDDEN + ncol] = (__bf16)(ov * tanh_fast(cnew));
        }
    }
}

__global__ __launch_bounds__(128, 2) void out_step(
    const __bf16* __restrict__ h, const __bf16* __restrict__ wout,
    const float* __restrict__ b_out, float* __restrict__ out, int t) {

    const int lane = threadIdx.x & 63;
    const int wave = threadIdx.x >> 6;
    const int r = lane & 31;
    const int koff = (lane >> 5) * 8;

    const int bid = blockIdx.x;
    const int mBase = ((bid & 7) << 10) + ((bid >> 3) << 5);
    const int nBase = wave * 32;

    f32x16 acc;
#pragma unroll
    for (int v = 0; v < 16; ++v) acc[v] = 0.0f;

    const __bf16* ap = h + (mBase + r) * HIDDEN + koff;
    const __bf16* bp = wout + (nBase + r) * HIDDEN + koff;
#pragma unroll 8
    for (int kk = 0; kk < HIDDEN / 16; ++kk) {
        bf16x8 a = *reinterpret_cast<const bf16x8*>(ap + kk * 16);
        bf16x8 b = *reinterpret_cast<const bf16x8*>(bp + kk * 16);
        acc = __builtin_amdgcn_mfma_f32_32x32x16_bf16(a, b, acc, 0, 0, 0);
    }

    const int col = nBase + r;
    const float bv = b_out[col];
    const int rbase = 4 * (lane >> 5);
#pragma unroll
    for (int v = 0; v < 16; ++v) {
        int row = mBase + (v & 3) + 8 * (v >> 2) + rbase;
        out[row * (STEPS * OUTPUT) + t * OUTPUT + col] = acc[v] + bv;
    }
}

extern "C" void kernel_launch(void* const* d_in, const int* in_sizes, int n_in,
                              void* d_out, int out_size, void* d_ws, size_t ws_size,
                              hipStream_t stream) {
    const float* W_ih   = (const float*)d_in[1];
    const float* W_hh   = (const float*)d_in[2];
    const float* b_lstm = (const float*)d_in[3];
    const float* h0     = (const float*)d_in[4];
    const float* c0     = (const float*)d_in[5];
    const float* W_out  = (const float*)d_in[6];
    const float* b_out  = (const float*)d_in[7];
    float* out = (float*)d_out;

    char* ws = (char*)d_ws;
    size_t off = 0;
    auto alloc = [&](size_t bytes) -> void* {
        void* p = ws + off;
        off += (bytes + 255) & ~(size_t)255;
        return p;
    };
    float*  wcomb = (float*)alloc((size_t)4 * HIDDEN * HIDDEN * 4);
    float*  bias1 = (float*)alloc((size_t)4 * HIDDEN * 4);
    __bf16* P0    = (__bf16*)alloc((size_t)16 * 8 * 128 * 64 * 2);
    __bf16* P1    = (__bf16*)alloc((size_t)16 * 8 * 128 * 64 * 2);
    __bf16* wout  = (__bf16*)alloc((size_t)OUTPUT * HIDDEN * 2);
    __bf16* hA    = (__bf16*)alloc((size_t)BATCH * HIDDEN * 2);
    __bf16* hB    = (__bf16*)alloc((size_t)BATCH * HIDDEN * 2);
    float*  c     = (float*)alloc((size_t)BATCH * HIDDEN * 4);

    fold_weights<<<4 * HIDDEN, 64, 0, stream>>>(W_ih, W_hh, W_out, b_lstm, b_out, wcomb, bias1);
    pack_weights<<<2048, 256, 0, stream>>>(W_hh, wcomb, W_out, P0, P1, wout);
    init_state<<<(BATCH * HIDDEN + 255) / 256, 256, 0, stream>>>(h0, c0, hA, c);

    // --- cooperative persistent path with deterministic fallback ---
    bool coop = false;
    int maxAct = 0;
    if (hipOccupancyMaxActiveBlocksPerMultiprocessor(&maxAct, lstm_persistent, 512, 0)
            == hipSuccess && maxAct >= 1) {
        const __bf16* cP0 = P0; const __bf16* cP1 = P1;
        const float* cb0 = b_lstm; const float* cb1 = bias1;
        const __bf16* cwo = wout; const float* cbo = b_out;
        const float* cc0 = c0; __bf16* chA = hA; __bf16* chB = hB; float* cout = out;
        void* args[] = { (void*)&cP0, (void*)&cP1, (void*)&cb0, (void*)&cb1,
                         (void*)&cwo, (void*)&cbo, (void*)&cc0, (void*)&chA, (void*)&chB,
                         (void*)&cout };
        coop = (hipLaunchCooperativeKernel((void*)lstm_persistent, dim3(256), dim3(512),
                                           args, 0, stream) == hipSuccess);
    }
    if (!coop) {
        __bf16* hc = hA;
        __bf16* hn = hB;
        for (int t = 0; t < STEPS; ++t) {
            const __bf16* P    = (t == 0) ? P0 : P1;
            const float*  bias = (t == 0) ? b_lstm : bias1;
            lstm_step<<<512, 256, 0, stream>>>(hc, P, bias, c, hn);
            out_step<<<BATCH / 32, 128, 0, stream>>>(hn, wout, b_out, out, t);
            __bf16* tmp = hc; hc = hn; hn = tmp;
        }
    }
}

// Round 11
// 4283.763 us; speedup vs baseline: 1.0324x; 1.0262x over previous
//
#include <hip/hip_runtime.h>
#include <hip/hip_bf16.h>

#define BATCH 8192
#define HIDDEN 512
#define OUTPUT 64
#define STEPS 100

typedef __bf16 bf16x8 __attribute__((ext_vector_type(8)));
typedef float f32x16 __attribute__((ext_vector_type(16)));

__device__ __forceinline__ float sigf(float x) { return 1.0f / (1.0f + __expf(-x)); }
// tanh(x) = 1 - 2/(1+exp(2x)); saturates correctly at +/-inf
__device__ __forceinline__ float tanh_fast(float x) { return 1.0f - 2.0f / (1.0f + __expf(2.0f * x)); }

// ---------------- fold: wcomb = Whh + Wih@Wout (fp32), bias1 = b_lstm + Wih@b_out ----------------
// inp_t = out_{t-1} = h_t@Wout^T + b_out  =>  for t>=1:
//   gates_t = h_t @ (Whh + Wih@Wout)^T + (b_lstm + Wih@b_out).   t=0: plain Whh/b_lstm (inp_0=0).
// (R7-proven numerics.)
__global__ __launch_bounds__(64) void fold_weights(
    const float* __restrict__ Wih, const float* __restrict__ Whh,
    const float* __restrict__ Wout, const float* __restrict__ b_lstm,
    const float* __restrict__ b_out, float* __restrict__ wcomb, float* __restrict__ bias1) {
    __shared__ float wrow[64];
    const int n = blockIdx.x;
    const int tid = threadIdx.x;
    wrow[tid] = Wih[n * 64 + tid];
    __syncthreads();
    for (int k = tid; k < HIDDEN; k += 64) {
        float s = Whh[n * HIDDEN + k];
#pragma unroll 16
        for (int o = 0; o < 64; ++o) s += wrow[o] * Wout[o * HIDDEN + k];
        wcomb[n * HIDDEN + k] = s;
    }
    if (tid == 0) {
        float s = b_lstm[n];
        for (int o = 0; o < 64; ++o) s += wrow[o] * b_out[o];
        bias1[n] = s;
    }
}

// ---------------- pack weights into B-fragment order (fp32 -> bf16) ----------------
// P layout: frag f = g*16 + fc (fc = hcol-frag 0..15), then kk = 0..31 (16-k steps):
//   P[(f*32 + kk)*512 + lane*8 + e] = W[n][k],  n = g*512 + fc*32 + (lane&31),
//   k = kk*16 + (lane>>5)*8 + e.
// Each 1KB frag is exactly one wave's 32x32x16-MFMA B operand (col=lane&31, k=(lane>>5)*8+e),
// loaded as one coalesced global_load_dwordx4 per lane. No LDS needed for B (no CU-level reuse:
// waves own disjoint columns).
__global__ void pack_weights(const float* __restrict__ Whh, const float* __restrict__ wcomb,
                             const float* __restrict__ Wout,
                             __bf16* __restrict__ P0, __bf16* __restrict__ P1,
                             __bf16* __restrict__ WOp) {
    const int NP = 64 * 32 * 512;   // 1048576
    for (int idx = blockIdx.x * 256 + threadIdx.x; idx < NP; idx += gridDim.x * 256) {
        int e    = idx & 7;
        int lane = (idx >> 3) & 63;
        int kk   = (idx >> 9) & 31;
        int f    = idx >> 14;          // 0..63
        int g = f >> 4, fc = f & 15;
        int n = g * 512 + fc * 32 + (lane & 31);
        int k = kk * 16 + ((lane >> 5) << 3) + e;
        P0[idx] = (__bf16)Whh[n * HIDDEN + k];
        P1[idx] = (__bf16)wcomb[n * HIDDEN + k];
    }
    // W_out pack: 2 ocol-frags x 32 kk
    for (int idx = blockIdx.x * 256 + threadIdx.x; idx < 2 * 32 * 512; idx += gridDim.x * 256) {
        int e    = idx & 7;
        int lane = (idx >> 3) & 63;
        int kk   = (idx >> 9) & 31;
        int fc2  = idx >> 14;          // 0..1
        int no = fc2 * 32 + (lane & 31);
        int k  = kk * 16 + ((lane >> 5) << 3) + e;
        WOp[idx] = (__bf16)Wout[no * HIDDEN + k];
    }
}

// ================= row-partitioned persistent kernel: ZERO inter-block sync =================
// 256 blocks x 512 thr (1/CU, 8 waves). Block owns batch rows [32*bid, +32) for ALL 100 steps:
//   h (32x512 bf16) in LDS, c in registers -> recurrence is block-local; no grid.sync,
//   no cooperative launch, no global h. 2 __syncthreads/step (h_lds RAW/WAR).
// Wave w owns hcols [w*64,+64) across all 4 gates: acc[g][cf] = 32 rows x 32 cols.
// B read per wave per k-step: 8 frags (4g x 2cf) direct from L2-resident packed P (2MB,
// shared by all 32 blocks on an XCD's L2).
// h_lds XOR-swizzle: byte = row*1024 + (colByte ^ ((row&7)<<4)) — A-reads (ds_read_b128,
// 32 rows at same col-range) spread over 8 bank-quads (~4-way residual; (r&15)<<4 variant
// deferred until this structure has one verified bench).
// Per-step out GEMM (waves 0,1) overlaps waves 2-7 entering the next step's gates.
__global__ __launch_bounds__(512, 2) void lstm_rows(
    const __bf16* __restrict__ P0, const __bf16* __restrict__ P1,
    const float* __restrict__ bias0, const float* __restrict__ bias1,
    const __bf16* __restrict__ WO, const float* __restrict__ b_out,
    const float* __restrict__ h0, const float* __restrict__ c0,
    float* __restrict__ out) {

    __shared__ __bf16 hlds[32 * 512];   // 32 KB, swizzled
    char* hb = (char*)hlds;

    const int tid  = threadIdx.x;
    const int lane = tid & 63;
    const int wave = tid >> 6;        // 0..7
    const int r    = lane & 31;
    const int hi   = lane >> 5;
    const int rbase = 4 * hi;
    const int rowBase = blockIdx.x * 32;

    // init h_lds = h0 broadcast (swizzled write)
    for (int i = tid; i < 32 * 512; i += 512) {
        int row = i >> 9, col = i & 511;
        *(__bf16*)(hb + row * 1024 + ((col * 2) ^ ((row & 7) << 4))) = (__bf16)h0[col];
    }

    // register cell state: thread owns (16 rows-frags) x 2 col-frags at hcols hc0, hc1
    const int hc0 = wave * 64 + r;
    const int hc1 = hc0 + 32;
    float creg0[16], creg1[16];
    {
        const float cA = c0[hc0], cB = c0[hc1];
#pragma unroll
        for (int v = 0; v < 16; ++v) { creg0[v] = cA; creg1[v] = cB; }
    }
    // bias registers for current step-set (t=0 uses bias0; swapped to bias1 after step 0)
    float bA[4], bB[4];
#pragma unroll
    for (int g = 0; g < 4; ++g) { bA[g] = bias0[g * HIDDEN + hc0]; bB[g] = bias0[g * HIDDEN + hc1]; }

    float bv = 0.0f;
    if (wave < 2) bv = b_out[wave * 32 + r];

    const int swz   = (r & 7) << 4;
    const int abase = r * 1024;
    const __bf16* P = P0;

    __syncthreads();   // h_lds init visible

    for (int t = 0; t < STEPS; ++t) {
        f32x16 acc[4][2];
#pragma unroll
        for (int g = 0; g < 4; ++g)
#pragma unroll
            for (int cf = 0; cf < 2; ++cf)
#pragma unroll
                for (int v = 0; v < 16; ++v) acc[g][cf][v] = 0.0f;

        // gates GEMM: 32 k-steps; per step: 1 LDS A-frag + 8 global B-frags + 8 MFMA
#pragma unroll 4
        for (int kk = 0; kk < 32; ++kk) {
            bf16x8 a = *(const bf16x8*)(hb + abase + ((kk * 32 + hi * 16) ^ swz));
#pragma unroll
            for (int g = 0; g < 4; ++g) {
                const __bf16* bp0 = P + (((g * 16 + 2 * wave + 0) * 32 + kk) << 9) + lane * 8;
                const __bf16* bp1 = P + (((g * 16 + 2 * wave + 1) * 32 + kk) << 9) + lane * 8;
                acc[g][0] = __builtin_amdgcn_mfma_f32_32x32x16_bf16(
                    a, *(const bf16x8*)bp0, acc[g][0], 0, 0, 0);
                acc[g][1] = __builtin_amdgcn_mfma_f32_32x32x16_bf16(
                    a, *(const bf16x8*)bp1, acc[g][1], 0, 0, 0);
            }
        }
        __syncthreads();   // all waves done READING h_lds (WAR guard before epilogue writes)

        // cell epilogue: C/D map col=lane&31, row=(v&3)+8*(v>>2)+4*hi; h_lds updated in place
#pragma unroll
        for (int v = 0; v < 16; ++v) {
            const int row = rbase + (v & 3) + 8 * (v >> 2);
            const int rswz = (row & 7) << 4;
            {
                float i_ = sigf(acc[0][0][v] + bA[0]);
                float f_ = sigf(acc[1][0][v] + bA[1]);
                float g_ = tanh_fast(acc[2][0][v] + bA[2]);
                float o_ = sigf(acc[3][0][v] + bA[3]);
                float cn = f_ * creg0[v] + i_ * g_;
                creg0[v] = cn;
                *(__bf16*)(hb + row * 1024 + ((hc0 * 2) ^ rswz)) = (__bf16)(o_ * tanh_fast(cn));
            }
            {
                float i_ = sigf(acc[0][1][v] + bB[0]);
                float f_ = sigf(acc[1][1][v] + bB[1]);
                float g_ = tanh_fast(acc[2][1][v] + bB[2]);
                float o_ = sigf(acc[3][1][v] + bB[3]);
                float cn = f_ * creg1[v] + i_ * g_;
                creg1[v] = cn;
                *(__bf16*)(hb + row * 1024 + ((hc1 * 2) ^ rswz)) = (__bf16)(o_ * tanh_fast(cn));
            }
        }
        __syncthreads();   // h_{t+1} visible to all waves (RAW guard)

        if (t == 0) {      // switch to folded weights/bias for t>=1
            P = P1;
#pragma unroll
            for (int g = 0; g < 4; ++g) {
                bA[g] = bias1[g * HIDDEN + hc0];
                bB[g] = bias1[g * HIDDEN + hc1];
            }
        }

        // out_t = h_{t+1} @ Wout^T + b_out (waves 0,1; overlaps waves 2-7's next gates).
        // Safe: epilogue(t+1) writes h_lds only after barrier#1(t+1), which waves 0,1
        // reach only after finishing this block.
        if (wave < 2) {
            f32x16 oacc;
#pragma unroll
            for (int v = 0; v < 16; ++v) oacc[v] = 0.0f;
#pragma unroll 4
            for (int kk = 0; kk < 32; ++kk) {
                bf16x8 a = *(const bf16x8*)(hb + abase + ((kk * 32 + hi * 16) ^ swz));
                const __bf16* bp = WO + ((wave * 32 + kk) << 9) + lane * 8;
                oacc = __builtin_amdgcn_mfma_f32_32x32x16_bf16(
                    a, *(const bf16x8*)bp, oacc, 0, 0, 0);
            }
            const int ocol = wave * 32 + r;
#pragma unroll
            for (int v = 0; v < 16; ++v) {
                const int row = rbase + (v & 3) + 8 * (v >> 2);
                out[(size_t)(rowBase + row) * (STEPS * OUTPUT) + t * OUTPUT + ocol] = oacc[v] + bv;
            }
        }
    }
}

extern "C" void kernel_launch(void* const* d_in, const int* in_sizes, int n_in,
                              void* d_out, int out_size, void* d_ws, size_t ws_size,
                              hipStream_t stream) {
    // inputs: x(unused — reference zeroes initial context), W_ih, W_hh, b_lstm,
    //         h0, c0, W_out, b_out, steps
    const float* W_ih   = (const float*)d_in[1];
    const float* W_hh   = (const float*)d_in[2];
    const float* b_lstm = (const float*)d_in[3];
    const float* h0     = (const float*)d_in[4];
    const float* c0     = (const float*)d_in[5];
    const float* W_out  = (const float*)d_in[6];
    const float* b_out  = (const float*)d_in[7];
    float* out = (float*)d_out;

    char* ws = (char*)d_ws;
    size_t off = 0;
    auto alloc = [&](size_t bytes) -> void* {
        void* p = ws + off;
        off += (bytes + 255) & ~(size_t)255;
        return p;
    };
    float*  wcomb = (float*)alloc((size_t)4 * HIDDEN * HIDDEN * 4);   // 4 MB fp32
    float*  bias1 = (float*)alloc((size_t)4 * HIDDEN * 4);
    __bf16* P0    = (__bf16*)alloc((size_t)64 * 32 * 512 * 2);        // 2 MB frag-packed
    __bf16* P1    = (__bf16*)alloc((size_t)64 * 32 * 512 * 2);        // 2 MB
    __bf16* WOp   = (__bf16*)alloc((size_t)2 * 32 * 512 * 2);         // 64 KB

    fold_weights<<<4 * HIDDEN, 64, 0, stream>>>(W_ih, W_hh, W_out, b_lstm, b_out, wcomb, bias1);
    pack_weights<<<2048, 256, 0, stream>>>(W_hh, wcomb, W_out, P0, P1, WOp);

    // plain launch — no cooperative API, no fallback needed
    lstm_rows<<<BATCH / 32, 512, 0, stream>>>(P0, P1, b_lstm, bias1, WOp, b_out, h0, c0, out);
}

// Round 13
// 3366.861 us; speedup vs baseline: 1.3135x; 1.2723x over previous
//
#include <hip/hip_runtime.h>
#include <hip/hip_bf16.h>

#define BATCH 8192
#define HIDDEN 512
#define OUTPUT 64
#define STEPS 100

typedef __bf16 bf16x8 __attribute__((ext_vector_type(8)));
typedef float f32x16 __attribute__((ext_vector_type(16)));

__device__ __forceinline__ float sigf(float x) { return 1.0f / (1.0f + __expf(-x)); }
// tanh(x) = 1 - 2/(1+exp(2x)); saturates correctly at +/-inf
__device__ __forceinline__ float tanh_fast(float x) { return 1.0f - 2.0f / (1.0f + __expf(2.0f * x)); }

// ---------------- fold: wcomb = Whh + Wih@Wout (fp32), bias1 = b_lstm + Wih@b_out ----------------
// inp_t = out_{t-1} = h_t@Wout^T + b_out  =>  for t>=1:
//   gates_t = h_t @ (Whh + Wih@Wout)^T + (b_lstm + Wih@b_out).   t=0: plain Whh/b_lstm (inp_0=0).
// (R7-proven numerics.)
__global__ __launch_bounds__(64) void fold_weights(
    const float* __restrict__ Wih, const float* __restrict__ Whh,
    const float* __restrict__ Wout, const float* __restrict__ b_lstm,
    const float* __restrict__ b_out, float* __restrict__ wcomb, float* __restrict__ bias1) {
    __shared__ float wrow[64];
    const int n = blockIdx.x;
    const int tid = threadIdx.x;
    wrow[tid] = Wih[n * 64 + tid];
    __syncthreads();
    for (int k = tid; k < HIDDEN; k += 64) {
        float s = Whh[n * HIDDEN + k];
#pragma unroll 16
        for (int o = 0; o < 64; ++o) s += wrow[o] * Wout[o * HIDDEN + k];
        wcomb[n * HIDDEN + k] = s;
    }
    if (tid == 0) {
        float s = b_lstm[n];
        for (int o = 0; o < 64; ++o) s += wrow[o] * b_out[o];
        bias1[n] = s;
    }
}

// ---------------- pack weights into B-fragment order (fp32 -> bf16) ----------------
// P layout: frag f = g*16 + fc (fc = hcol-frag 0..15), then kk = 0..31 (16-k steps):
//   P[(f*32 + kk)*512 + lane*8 + e] = W[n][k],  n = g*512 + fc*32 + (lane&31),
//   k = kk*16 + (lane>>5)*8 + e.
// Each 1KB frag is one wave's 32x32x16-MFMA B operand (col=lane&31, k=(lane>>5)*8+e),
// one coalesced dwordx4 per lane. fc == wave index in the 16-wave main kernel.
__global__ void pack_weights(const float* __restrict__ Whh, const float* __restrict__ wcomb,
                             const float* __restrict__ Wout,
                             __bf16* __restrict__ P0, __bf16* __restrict__ P1,
                             __bf16* __restrict__ WOp) {
    const int NP = 64 * 32 * 512;   // 1048576
    for (int idx = blockIdx.x * 256 + threadIdx.x; idx < NP; idx += gridDim.x * 256) {
        int e    = idx & 7;
        int lane = (idx >> 3) & 63;
        int kk   = (idx >> 9) & 31;
        int f    = idx >> 14;          // 0..63
        int g = f >> 4, fc = f & 15;
        int n = g * 512 + fc * 32 + (lane & 31);
        int k = kk * 16 + ((lane >> 5) << 3) + e;
        P0[idx] = (__bf16)Whh[n * HIDDEN + k];
        P1[idx] = (__bf16)wcomb[n * HIDDEN + k];
    }
    // W_out pack: 2 ocol-frags x 32 kk
    for (int idx = blockIdx.x * 256 + threadIdx.x; idx < 2 * 32 * 512; idx += gridDim.x * 256) {
        int e    = idx & 7;
        int lane = (idx >> 3) & 63;
        int kk   = (idx >> 9) & 31;
        int fc2  = idx >> 14;          // 0..1
        int no = fc2 * 32 + (lane & 31);
        int k  = kk * 16 + ((lane >> 5) << 3) + e;
        WOp[idx] = (__bf16)Wout[no * HIDDEN + k];
    }
}

// ================= row-partitioned recurrence, 16 waves/block (4 waves/SIMD) =================
// 256 blocks x 1024 thr. Block owns batch rows [32*bid,+32) for all 100 steps: h in LDS,
// c in registers, zero inter-block traffic (R11-proven). R12 change: 16 waves (was 8) ->
// 4 waves/SIMD to hide the ~200-300cyc L2 latency on B-fragment loads that R11's counters
// showed dominating (390 TF effective ~= m102's plain-HIP rate at this GEMM size with 2
// waves/SIMD; Occupancy was 23.7%). Wave owns 32 gate-cols (acc 64 VGPR, total ~124 < 128
// cap of launch_bounds(1024,4) -> no creg spill).
// h_lds swizzle upgraded (r&15)<<4: A-reads 4-way -> 2-way bank aliasing (free, m136).
__global__ __launch_bounds__(1024, 4) void lstm_rows(
    const __bf16* __restrict__ P0, const __bf16* __restrict__ P1,
    const float* __restrict__ bias0, const float* __restrict__ bias1,
    const __bf16* __restrict__ WO, const float* __restrict__ b_out,
    const float* __restrict__ h0, const float* __restrict__ c0,
    float* __restrict__ out) {

    __shared__ __bf16 hlds[32 * 512];   // 32 KB, swizzled
    char* hb = (char*)hlds;

    const int tid  = threadIdx.x;
    const int lane = tid & 63;
    const int wave = tid >> 6;        // 0..15
    const int r    = lane & 31;
    const int hi   = lane >> 5;
    const int rbase = 4 * hi;
    const int rowBase = blockIdx.x * 32;

    // init h_lds = h0 broadcast (swizzled write)
    for (int i = tid; i < 32 * 512; i += 1024) {
        int row = i >> 9, col = i & 511;
        *(__bf16*)(hb + row * 1024 + ((col * 2) ^ ((row & 15) << 4))) = (__bf16)h0[col];
    }

    // register cell state: thread owns 16 rows at hidden col hc
    const int hc = wave * 32 + r;
    float creg[16];
    {
        const float cA = c0[hc];
#pragma unroll
        for (int v = 0; v < 16; ++v) creg[v] = cA;
    }
    // bias registers (t=0 uses bias0; switched to bias1 after step 0's epilogue)
    float bA[4];
#pragma unroll
    for (int g = 0; g < 4; ++g) bA[g] = bias0[g * HIDDEN + hc];

    float bv = 0.0f;
    if (wave < 2) bv = b_out[wave * 32 + r];

    const int swz   = (r & 15) << 4;
    const int abase = r * 1024;

    __syncthreads();   // h_lds init visible

    for (int t = 0; t < STEPS; ++t) {
        const __bf16* P = (t == 0) ? P0 : P1;

        f32x16 acc[4];
#pragma unroll
        for (int g = 0; g < 4; ++g)
#pragma unroll
            for (int v = 0; v < 16; ++v) acc[g][v] = 0.0f;

        // gates GEMM: 32 k-steps; per step: 1 LDS A-frag + 4 global B-frags + 4 MFMA
#pragma unroll 4
        for (int kk = 0; kk < 32; ++kk) {
            bf16x8 a = *(const bf16x8*)(hb + abase + ((kk * 32 + hi * 16) ^ swz));
#pragma unroll
            for (int g = 0; g < 4; ++g) {
                const __bf16* bp = P + (((g * 16 + wave) * 32 + kk) << 9) + lane * 8;
                acc[g] = __builtin_amdgcn_mfma_f32_32x32x16_bf16(
                    a, *(const bf16x8*)bp, acc[g], 0, 0, 0);
            }
        }
        __syncthreads();   // all waves done READING h_lds (WAR guard before epilogue writes)

        // cell epilogue: C/D map col=lane&31, row=(v&3)+8*(v>>2)+4*hi; h_lds updated in place
#pragma unroll
        for (int v = 0; v < 16; ++v) {
            const int row = rbase + (v & 3) + 8 * (v >> 2);
            float i_ = sigf(acc[0][v] + bA[0]);
            float f_ = sigf(acc[1][v] + bA[1]);
            float g_ = tanh_fast(acc[2][v] + bA[2]);
            float o_ = sigf(acc[3][v] + bA[3]);
            float cn = f_ * creg[v] + i_ * g_;
            creg[v] = cn;
            *(__bf16*)(hb + row * 1024 + ((hc * 2) ^ ((row & 15) << 4))) = (__bf16)(o_ * tanh_fast(cn));
        }
        __syncthreads();   // h_{t+1} visible to all waves (RAW guard)

        if (t == 0) {      // folded weights/bias from step 1 onward
#pragma unroll
            for (int g = 0; g < 4; ++g) bA[g] = bias1[g * HIDDEN + hc];
        }

        // out_t = h_{t+1} @ Wout^T + b_out (waves 0,1; waves 2-15 proceed into next gates)
        if (wave < 2) {
            f32x16 oacc;
#pragma unroll
            for (int v = 0; v < 16; ++v) oacc[v] = 0.0f;
#pragma unroll 4
            for (int kk = 0; kk < 32; ++kk) {
                bf16x8 a = *(const bf16x8*)(hb + abase + ((kk * 32 + hi * 16) ^ swz));
                const __bf16* bp = WO + ((wave * 32 + kk) << 9) + lane * 8;
                oacc = __builtin_amdgcn_mfma_f32_32x32x16_bf16(
                    a, *(const bf16x8*)bp, oacc, 0, 0, 0);
            }
            const int ocol = wave * 32 + r;
#pragma unroll
            for (int v = 0; v < 16; ++v) {
                const int row = rbase + (v & 3) + 8 * (v >> 2);
                out[(size_t)(rowBase + row) * (STEPS * OUTPUT) + t * OUTPUT + ocol] = oacc[v] + bv;
            }
        }
    }
}

extern "C" void kernel_launch(void* const* d_in, const int* in_sizes, int n_in,
                              void* d_out, int out_size, void* d_ws, size_t ws_size,
                              hipStream_t stream) {
    // inputs: x(unused — reference zeroes initial context), W_ih, W_hh, b_lstm,
    //         h0, c0, W_out, b_out, steps
    const float* W_ih   = (const float*)d_in[1];
    const float* W_hh   = (const float*)d_in[2];
    const float* b_lstm = (const float*)d_in[3];
    const float* h0     = (const float*)d_in[4];
    const float* c0     = (const float*)d_in[5];
    const float* W_out  = (const float*)d_in[6];
    const float* b_out  = (const float*)d_in[7];
    float* out = (float*)d_out;

    char* ws = (char*)d_ws;
    size_t off = 0;
    auto alloc = [&](size_t bytes) -> void* {
        void* p = ws + off;
        off += (bytes + 255) & ~(size_t)255;
        return p;
    };
    float*  wcomb = (float*)alloc((size_t)4 * HIDDEN * HIDDEN * 4);   // 4 MB fp32
    float*  bias1 = (float*)alloc((size_t)4 * HIDDEN * 4);
    __bf16* P0    = (__bf16*)alloc((size_t)64 * 32 * 512 * 2);        // 2 MB frag-packed
    __bf16* P1    = (__bf16*)alloc((size_t)64 * 32 * 512 * 2);        // 2 MB
    __bf16* WOp   = (__bf16*)alloc((size_t)2 * 32 * 512 * 2);         // 64 KB

    fold_weights<<<4 * HIDDEN, 64, 0, stream>>>(W_ih, W_hh, W_out, b_lstm, b_out, wcomb, bias1);
    pack_weights<<<2048, 256, 0, stream>>>(W_hh, wcomb, W_out, P0, P1, WOp);

    lstm_rows<<<BATCH / 32, 1024, 0, stream>>>(P0, P1, b_lstm, bias1, WOp, b_out, h0, c0, out);
}